// Round 4
// baseline (309.672 us; speedup 1.0000x reference)
//
#include <hip/hip_runtime.h>
#include <stdint.h>

typedef unsigned short ushort_t;
typedef __bf16 bf16x8 __attribute__((ext_vector_type(8)));
typedef float f32x4 __attribute__((ext_vector_type(4)));
typedef unsigned short ushort8 __attribute__((ext_vector_type(8)));

#define DEV static __device__ __forceinline__

DEV unsigned short f2bf(float f) {
    union { float f; unsigned int i; } v; v.f = f;
    unsigned int u = v.i;
    return (unsigned short)((u + 0x7fffu + ((u >> 16) & 1u)) >> 16);
}
DEV float bf2f(unsigned short u) {
    union { unsigned int i; float f; } v; v.i = ((unsigned int)u) << 16; return v.f;
}

// ---------------------------------------------------------------------------
// fp32 -> bf16 weight conversion
// ---------------------------------------------------------------------------
__global__ __launch_bounds__(256) void cvt_kernel(
    const float* __restrict__ in, ushort_t* __restrict__ out, int n)
{
    int i = blockIdx.x * 256 + threadIdx.x;
    if (i < n) out[i] = f2bf(in[i]);
}

// ---------------------------------------------------------------------------
// 3-NN: 4-way candidate split (unchanged from round 3 — was the fix).
// ---------------------------------------------------------------------------
__global__ __launch_bounds__(256) void knn_kernel(
    const float* __restrict__ xyz1, const float* __restrict__ xyz2,
    int* __restrict__ idx_out, float* __restrict__ w_out)
{
    __shared__ float4 P[1024];
    __shared__ float mD[12][64];
    __shared__ int   mI[12][64];
    const int b = blockIdx.y;
    const int tid = threadIdx.x;
    for (int s = tid; s < 1024; s += 256) {
        const float* p = xyz2 + ((size_t)b * 1024 + s) * 3;
        float x = p[0], y = p[1], z = p[2];
        float pp = __fadd_rn(__fadd_rn(__fmul_rn(x, x), __fmul_rn(y, y)), __fmul_rn(z, z));
        P[s] = make_float4(x, y, z, pp);
    }
    __syncthreads();
    const int ql = tid & 63;
    const int chunk = tid >> 6;
    const int n = blockIdx.x * 64 + ql;
    const float* q = xyz1 + ((size_t)b * 4096 + n) * 3;
    float qx = q[0], qy = q[1], qz = q[2];
    float qq = __fadd_rn(__fadd_rn(__fmul_rn(qx, qx), __fmul_rn(qy, qy)), __fmul_rn(qz, qz));
    float d0 = 1e30f, d1 = 1e30f, d2 = 1e30f;
    int i0 = 0, i1 = 0, i2 = 0;
    const int s0 = chunk * 256;
#pragma unroll 4
    for (int s = s0; s < s0 + 256; ++s) {
        float4 p = P[s];
        float dot = __fadd_rn(__fadd_rn(__fmul_rn(qx, p.x), __fmul_rn(qy, p.y)), __fmul_rn(qz, p.z));
        float d = __fsub_rn(__fadd_rn(qq, p.w), __fmul_rn(2.0f, dot));
        if (d < d2) {
            if (d < d1) {
                d2 = d1; i2 = i1;
                if (d < d0) { d1 = d0; i1 = i0; d0 = d; i0 = s; }
                else        { d1 = d;  i1 = s; }
            } else { d2 = d; i2 = s; }
        }
    }
    mD[chunk * 3 + 0][ql] = d0; mI[chunk * 3 + 0][ql] = i0;
    mD[chunk * 3 + 1][ql] = d1; mI[chunk * 3 + 1][ql] = i1;
    mD[chunk * 3 + 2][ql] = d2; mI[chunk * 3 + 2][ql] = i2;
    __syncthreads();
    if (tid < 64) {
        float e0 = 1e30f, e1 = 1e30f, e2 = 1e30f;
        int j0 = 0, j1 = 0, j2 = 0;
#pragma unroll
        for (int c = 0; c < 12; ++c) {
            float d = mD[c][ql]; int i = mI[c][ql];
            if (d < e2) {
                if (d < e1) {
                    e2 = e1; j2 = j1;
                    if (d < e0) { e1 = e0; j1 = j0; e0 = d; j0 = i; }
                    else        { e1 = d;  j1 = i; }
                } else { e2 = d; j2 = i; }
            }
        }
        float r0 = 1.0f / (e0 + 1e-8f);
        float r1 = 1.0f / (e1 + 1e-8f);
        float r2 = 1.0f / (e2 + 1e-8f);
        float rs = __fadd_rn(__fadd_rn(r0, r1), r2);
        size_t o = ((size_t)b * 4096 + n) * 3;
        idx_out[o + 0] = j0; idx_out[o + 1] = j1; idx_out[o + 2] = j2;
        w_out[o + 0] = r0 / rs; w_out[o + 1] = r1 / rs; w_out[o + 2] = r2 / rs;
    }
}

DEV void cvt8(const float4& u0, const float4& u1, ushort8& hv) {
    hv[0] = f2bf(u0.x); hv[1] = f2bf(u0.y); hv[2] = f2bf(u0.z); hv[3] = f2bf(u0.w);
    hv[4] = f2bf(u1.x); hv[5] = f2bf(u1.y); hv[6] = f2bf(u1.z); hv[7] = f2bf(u1.w);
}

// ---------------------------------------------------------------------------
// GEMM1 v2: y1 = [points1 | interp](64x512 tile) @ w1^T, barrier-free K-loop.
// Stage 1 (once per block): build the FULL bf16 A tile in LDS — points1 cvt
// plus on-the-fly 3-NN interp (each source row gathered exactly once, all
// loads issued with full MLP). LDS = 64x512 bf16 = 64 KB exactly, XOR-swizzled
// in 16B blocks by (row&7) to break the 1024B-row-stride bank aliasing.
// K-loop: A frags from LDS, B frags per-lane from L2-resident w1b, both
// register-double-buffered; NO __syncthreads inside -> no vmcnt(0) drains.
// Epilogue: bf16 y1 store + fused BN stats (shfl over fq, 1 atomic/col).
// ---------------------------------------------------------------------------
__global__ __launch_bounds__(256) void gemm1_kernel(
    const float* __restrict__ p1, const float* __restrict__ points2,
    const int* __restrict__ idx, const float* __restrict__ wgt,
    const ushort_t* __restrict__ w1b, ushort_t* __restrict__ y,
    float* __restrict__ sums, float* __restrict__ sqs)
{
    __shared__ ushort_t As[64 * 512];   // 64 KB, swizzled
    const int tid = threadIdx.x;
    const int wave = tid >> 6, lane = tid & 63;
    const int frl = lane & 15, fq = lane >> 4;
    const int fr7 = frl & 7;
    const int m0 = blockIdx.x * 64;

    // ---- stage 1: A tile -> LDS ----
    {
        const int r = tid >> 2, cg = tid & 3;     // row 0..63, col-group of 64
        ushort_t* dst = As + r * 512;
        const float4* gp = (const float4*)(p1 + (size_t)(m0 + r) * 256 + cg * 64);
#pragma unroll
        for (int jj = 0; jj < 8; ++jj) {
            float4 u0 = gp[2 * jj], u1 = gp[2 * jj + 1];
            ushort8 hv; cvt8(u0, u1, hv);
            int cb = cg * 8 + jj;                  // 16B block index 0..31
            *(ushort8*)(dst + ((cb ^ (r & 7)) << 3)) = hv;
        }
        const size_t qo = (size_t)(m0 + r) * 3;
        int i0 = idx[qo], i1 = idx[qo + 1], i2 = idx[qo + 2];
        float w0 = wgt[qo], w1 = wgt[qo + 1], w2 = wgt[qo + 2];
        const float* pb = points2 + (size_t)(m0 >> 12) * (1024 * 256);
        const float4* g0 = (const float4*)(pb + (size_t)i0 * 256 + cg * 64);
        const float4* g1 = (const float4*)(pb + (size_t)i1 * 256 + cg * 64);
        const float4* g2 = (const float4*)(pb + (size_t)i2 * 256 + cg * 64);
#pragma unroll
        for (int jj = 0; jj < 8; ++jj) {
            float4 a0 = g0[2 * jj], a1 = g0[2 * jj + 1];
            float4 b0 = g1[2 * jj], b1 = g1[2 * jj + 1];
            float4 c0 = g2[2 * jj], c1 = g2[2 * jj + 1];
            float v[8];
            v[0] = fmaf(w2, c0.x, fmaf(w1, b0.x, __fmul_rn(w0, a0.x)));
            v[1] = fmaf(w2, c0.y, fmaf(w1, b0.y, __fmul_rn(w0, a0.y)));
            v[2] = fmaf(w2, c0.z, fmaf(w1, b0.z, __fmul_rn(w0, a0.z)));
            v[3] = fmaf(w2, c0.w, fmaf(w1, b0.w, __fmul_rn(w0, a0.w)));
            v[4] = fmaf(w2, c1.x, fmaf(w1, b1.x, __fmul_rn(w0, a1.x)));
            v[5] = fmaf(w2, c1.y, fmaf(w1, b1.y, __fmul_rn(w0, a1.y)));
            v[6] = fmaf(w2, c1.z, fmaf(w1, b1.z, __fmul_rn(w0, a1.z)));
            v[7] = fmaf(w2, c1.w, fmaf(w1, b1.w, __fmul_rn(w0, a1.w)));
            ushort8 hv;
#pragma unroll
            for (int j = 0; j < 8; ++j) hv[j] = f2bf(v[j]);
            int cb = 32 + cg * 8 + jj;
            *(ushort8*)(dst + ((cb ^ (r & 7)) << 3)) = hv;
        }
    }

    f32x4 acc[4][4];
#pragma unroll
    for (int i = 0; i < 4; ++i)
#pragma unroll
        for (int j = 0; j < 4; ++j) acc[i][j] = f32x4{0.0f, 0.0f, 0.0f, 0.0f};

    __syncthreads();   // the only barrier

    // ---- barrier-free K-loop, reg double-buffered A & B ----
    const ushort_t* wb = w1b + (size_t)(wave * 64 + frl) * 512 + fq * 8;
    bf16x8 aA[4], aB[4], bA[4], bB[4];

#define LOADB1(dst, kc) { _Pragma("unroll") \
    for (int j = 0; j < 4; ++j) dst[j] = *(const bf16x8*)(wb + j * (16 * 512) + (kc) * 32); }
#define LOADA1(dst, kc) { _Pragma("unroll") \
    for (int i = 0; i < 4; ++i) dst[i] = *(const bf16x8*)(As + (i * 16 + frl) * 512 + (((((kc) << 2) + fq) ^ fr7) << 3)); }
#define MF16(a, b) { _Pragma("unroll") \
    for (int i = 0; i < 4; ++i) { _Pragma("unroll") \
        for (int j = 0; j < 4; ++j) \
            acc[i][j] = __builtin_amdgcn_mfma_f32_16x16x32_bf16(a[i], b[j], acc[i][j], 0, 0, 0); } }

    LOADA1(aA, 0); LOADB1(bA, 0);
#pragma unroll
    for (int kc = 0; kc < 16; kc += 2) {
        LOADA1(aB, kc + 1); LOADB1(bB, kc + 1);
        MF16(aA, bA);
        if (kc + 2 < 16) { LOADA1(aA, kc + 2); LOADB1(bA, kc + 2); }
        MF16(aB, bB);
    }

    // ---- epilogue: store y1 bf16 + fused BN1 stats ----
#pragma unroll
    for (int j = 0; j < 4; ++j) {
        const int col = wave * 64 + j * 16 + frl;
        float s = 0.f, q = 0.f;
#pragma unroll
        for (int i = 0; i < 4; ++i)
#pragma unroll
            for (int rr = 0; rr < 4; ++rr) {
                ushort_t hb = f2bf(acc[i][j][rr]);
                float v = bf2f(hb);
                y[(size_t)(m0 + i * 16 + fq * 4 + rr) * 256 + col] = hb;
                s += v; q = fmaf(v, v, q);
            }
        s += __shfl_xor(s, 16); s += __shfl_xor(s, 32);
        q += __shfl_xor(q, 16); q += __shfl_xor(q, 32);
        if (fq == 0) { atomicAdd(&sums[col], s); atomicAdd(&sqs[col], q); }
    }
}

// ---------------------------------------------------------------------------
// GEMM2 v2: y2(fp32, d_out) = relu(bn1(y1)) @ w2^T, same barrier-free design.
// Stage 1: y1 tile + folded BN + relu -> bf16 LDS (64x264, pad 8).
// Epilogue: fp32 store + fused BN2 stats.
// ---------------------------------------------------------------------------
__global__ __launch_bounds__(256) void gemm2_kernel(
    const ushort_t* __restrict__ y1, const ushort_t* __restrict__ w2b,
    const float* __restrict__ a1, const float* __restrict__ c1,
    float* __restrict__ y2, float* __restrict__ sums, float* __restrict__ sqs)
{
    __shared__ ushort_t As[64 * 264];   // 33 KB, row pad +8 elems
    __shared__ float sA[256], sC[256];
    const int tid = threadIdx.x;
    const int wave = tid >> 6, lane = tid & 63;
    const int frl = lane & 15, fq = lane >> 4;
    const int m0 = blockIdx.x * 64;

    sA[tid] = a1[tid]; sC[tid] = c1[tid];
    __syncthreads();

    // ---- stage 1: A = bf16(relu(a1*y1 + c1)) -> LDS ----
    {
        const int r = tid >> 2, cg = tid & 3;
        const ushort8* gp = (const ushort8*)(y1 + (size_t)(m0 + r) * 256 + cg * 64);
        ushort_t* dst = As + r * 264 + cg * 64;
#pragma unroll
        for (int jj = 0; jj < 8; ++jj) {
            ushort8 raw = gp[jj];
            ushort8 hv;
#pragma unroll
            for (int j = 0; j < 8; ++j) {
                int ch = cg * 64 + jj * 8 + j;
                float v = bf2f(raw[j]);
                hv[j] = f2bf(fmaxf(fmaf(v, sA[ch], sC[ch]), 0.0f));
            }
            *(ushort8*)(dst + jj * 8) = hv;
        }
    }

    f32x4 acc[4][4];
#pragma unroll
    for (int i = 0; i < 4; ++i)
#pragma unroll
        for (int j = 0; j < 4; ++j) acc[i][j] = f32x4{0.0f, 0.0f, 0.0f, 0.0f};

    __syncthreads();

    const ushort_t* wb = w2b + (size_t)(wave * 64 + frl) * 256 + fq * 8;
    bf16x8 aA[4], aB[4], bA[4], bB[4];

#define LOADB2(dst, kc) { _Pragma("unroll") \
    for (int j = 0; j < 4; ++j) dst[j] = *(const bf16x8*)(wb + j * (16 * 256) + (kc) * 32); }
#define LOADA2(dst, kc) { _Pragma("unroll") \
    for (int i = 0; i < 4; ++i) dst[i] = *(const bf16x8*)(As + (i * 16 + frl) * 264 + (kc) * 32 + fq * 8); }

    LOADA2(aA, 0); LOADB2(bA, 0);
#pragma unroll
    for (int kc = 0; kc < 8; kc += 2) {
        LOADA2(aB, kc + 1); LOADB2(bB, kc + 1);
        MF16(aA, bA);
        if (kc + 2 < 8) { LOADA2(aA, kc + 2); LOADB2(bA, kc + 2); }
        MF16(aB, bB);
    }

    // ---- epilogue: fp32 store + fused BN2 stats ----
#pragma unroll
    for (int j = 0; j < 4; ++j) {
        const int col = wave * 64 + j * 16 + frl;
        float s = 0.f, q = 0.f;
#pragma unroll
        for (int i = 0; i < 4; ++i)
#pragma unroll
            for (int rr = 0; rr < 4; ++rr) {
                float v = acc[i][j][rr];
                y2[(size_t)(m0 + i * 16 + fq * 4 + rr) * 256 + col] = v;
                s += v; q = fmaf(v, v, q);
            }
        s += __shfl_xor(s, 16); s += __shfl_xor(s, 32);
        q += __shfl_xor(q, 16); q += __shfl_xor(q, 32);
        if (fq == 0) { atomicAdd(&sums[col], s); atomicAdd(&sqs[col], q); }
    }
}

__global__ __launch_bounds__(256) void finalize_kernel(
    const float* __restrict__ sums, const float* __restrict__ sqs,
    const float* __restrict__ g, const float* __restrict__ bias,
    float* __restrict__ a, float* __restrict__ c)
{
    const int ch = threadIdx.x;
    const float inv_n = 1.0f / 65536.0f;
    float mu = sums[ch] * inv_n;
    float var = fmaf(-mu, mu, sqs[ch] * inv_n);
    float is = 1.0f / sqrtf(var + 1e-5f);
    float aa = g[ch] * is;
    a[ch] = aa;
    c[ch] = fmaf(-mu, aa, bias[ch]);
}

// out = relu(a2[c]*y2 + c2[c]) in place (fp32, 4 elems/thread)
__global__ __launch_bounds__(256) void apply_kernel(
    float* __restrict__ y2, const float* __restrict__ a, const float* __restrict__ c)
{
    const size_t i = ((size_t)blockIdx.x * 256 + threadIdx.x) * 4;
    const int ch = (int)(i & 255);
    float4 v = *(const float4*)(y2 + i);
    const float4 av = *(const float4*)(a + ch);
    const float4 cv = *(const float4*)(c + ch);
    v.x = fmaxf(fmaf(v.x, av.x, cv.x), 0.0f);
    v.y = fmaxf(fmaf(v.y, av.y, cv.y), 0.0f);
    v.z = fmaxf(fmaf(v.z, av.z, cv.z), 0.0f);
    v.w = fmaxf(fmaf(v.w, av.w, cv.w), 0.0f);
    *(float4*)(y2 + i) = v;
}

extern "C" void kernel_launch(void* const* d_in, const int* in_sizes, int n_in,
                              void* d_out, int out_size, void* d_ws, size_t ws_size,
                              hipStream_t stream)
{
    const float* xyz1    = (const float*)d_in[0];
    const float* xyz2    = (const float*)d_in[1];
    const float* points1 = (const float*)d_in[2];
    const float* points2 = (const float*)d_in[3];
    const float* w1      = (const float*)d_in[4];
    const float* g1      = (const float*)d_in[5];
    const float* b1      = (const float*)d_in[6];
    const float* w2      = (const float*)d_in[7];
    const float* g2      = (const float*)d_in[8];
    const float* b2      = (const float*)d_in[9];
    float* out = (float*)d_out;

    char* ws = (char*)d_ws;
    float* sums1 = (float*)(ws + 0);
    float* sqs1  = (float*)(ws + 1024);
    float* a1    = (float*)(ws + 2048);
    float* c1    = (float*)(ws + 3072);
    float* sums2 = (float*)(ws + 4096);
    float* sqs2  = (float*)(ws + 5120);
    float* a2    = (float*)(ws + 6144);
    float* c2    = (float*)(ws + 7168);
    ushort_t* w1b = (ushort_t*)(ws + (64u << 10));    // 256 KB
    ushort_t* w2b = (ushort_t*)(ws + (320u << 10));   // 128 KB
    int*   idx   = (int*)(ws + (1u << 20));           // 768 KB
    float* wgt   = (float*)(ws + (2u << 20));         // 768 KB
    ushort_t* y1 = (ushort_t*)(ws + (4u << 20));      // 32 MB  (total ~36 MB)

    hipMemsetAsync(ws, 0, 8192, stream);  // zero BN stat accumulators
    cvt_kernel<<<dim3(512), 256, 0, stream>>>(w1, w1b, 131072);
    cvt_kernel<<<dim3(256), 256, 0, stream>>>(w2, w2b, 65536);
    knn_kernel<<<dim3(64, 16), 256, 0, stream>>>(xyz1, xyz2, idx, wgt);
    gemm1_kernel<<<dim3(1024), 256, 0, stream>>>(points1, points2, idx, wgt, w1b, y1, sums1, sqs1);
    finalize_kernel<<<dim3(1), 256, 0, stream>>>(sums1, sqs1, g1, b1, a1, c1);
    gemm2_kernel<<<dim3(1024), 256, 0, stream>>>(y1, w2b, a1, c1, out, sums2, sqs2);
    finalize_kernel<<<dim3(1), 256, 0, stream>>>(sums2, sqs2, g2, b2, a2, c2);
    apply_kernel<<<dim3(16384), 256, 0, stream>>>(out, a2, c2);
}